// Round 19
// baseline (79.509 us; speedup 1.0000x reference)
//
#include <hip/hip_runtime.h>
#include <hip/hip_bf16.h>

// ChebyKANLinear: y[b,j] = sum_i sum_k T_k(tanh(x[b,i])) * C[i,j,k]
// GEMM: M=16384, N=512, K=4608 (kflat = k*512 + i), k=0 folded into S0[j].
// v18 = v16 (balanced 64x64 wave tile; XCD-parity N-split; interleaved
//   produce/consume; depth-3 B reg prefetch; 1 barrier/ic; zero-conflict LDS)
//   + CYCLIC IC ROTATION: block starts at ic = S(bid) and walks mod 16.
//   Diagnosis: v16 is 50% matrix-fed with no pipe saturated -> the per-ic
//   barrier phase-locks each block, and co-resident blocks (Δbid=256, one
//   wave of each per SIMD) run in phase, so MFMA bursts collide. S differs
//   in bit 3 for Δbid=256 -> the two blocks anti-phase (produce overlaps
//   consume across blocks). Rotation is free: slabs wrap mod 16 within the
//   XCD-resident W2 half; x-prefetch wraps; no tail cases.

typedef __bf16 bf16x8 __attribute__((ext_vector_type(8)));
typedef float  f32x4  __attribute__((ext_vector_type(4)));

#define DIM  512
#define KDEG 9
#define NK   8               // k = 1..8 (k=0 folded into S0)
#define NIC  16
#define SLAB (4 * DIM * 8)   // 16384 bf16 per (k,ic) slab of W2

// ---- pack: C[i][j][k] -> W2[(k*16+ic)][s][j][e] (bf16), i = ic*32 + s*8 + e ----
__global__ void pack_w_kernel(const float* __restrict__ coeffs,
                              __bf16* __restrict__ W2) {
    int t  = blockIdx.x * blockDim.x + threadIdx.x;   // 32768 threads
    int j  = t & (DIM - 1);
    int s  = (t >> 9) & 3;
    int ic = t >> 11;

    bf16x8 v[KDEG];
#pragma unroll
    for (int e = 0; e < 8; ++e) {
        int i = ic * 32 + s * 8 + e;
        const float* src = coeffs + ((size_t)i * DIM + j) * KDEG;
#pragma unroll
        for (int k = 0; k < KDEG; ++k)
            v[k][e] = (__bf16)src[k];
    }
#pragma unroll
    for (int k = 0; k < KDEG; ++k) {
        size_t off = (size_t)(k * 16 + ic) * SLAB + ((size_t)s * DIM + j) * 8;
        *reinterpret_cast<bf16x8*>(W2 + off) = v[k];
    }
}

// ---- S0[j] = sum_i C[i][j][0] (f32) into W2's k=0 slab (GEMM never reads it) ----
__global__ void s0_kernel(const float* __restrict__ coeffs,
                          float* __restrict__ S0) {
    const int j    = blockIdx.x;      // 512 blocks
    const int lane = threadIdx.x;     // 64
    float s = 0.0f;
#pragma unroll
    for (int i = lane; i < DIM; i += 64)
        s += coeffs[((size_t)i * DIM + j) * KDEG];
#pragma unroll
    for (int off = 32; off > 0; off >>= 1)
        s += __shfl_down(s, off, 64);
    if (lane == 0) S0[j] = s;
}

// ---------------- fused GEMM: consume(ic) with produce(ic+1) interleaved --------
__global__ __launch_bounds__(256, 2) void cheby_gemm_kernel(
    const float* __restrict__ x,
    const __bf16* __restrict__ W2,
    float* __restrict__ out)
{
    // double-buffered A-tile: [buf][kk][row(64)][slot(4)][8] bf16, 2 x 32KB
    __shared__ __bf16 A_lds[2][NK][64][4][8];

    const int tid   = threadIdx.x;
    const int lane  = tid & 63;
    const int wid   = tid >> 6;      // 0..3 = n-group (64 cols each)
    const int l15   = lane & 15;
    const int l4    = lane >> 4;     // 0..3
    const int bid   = blockIdx.x;
    const int nhalf = bid & 1;                   // == XCD parity (XCD = bid%8)
    const int bm    = (bid >> 1) * 64;
    const int cb    = nhalf * 256 + wid * 64;    // wave's column base

    // cyclic ic start: bit3 from bid bit8 (co-resident pair Δbid=256 -> ΔS=8)
    const int S = (((bid >> 8) & 1) << 3) | ((bid >> 1) & 7);

    // ---- producer mapping: thread owns 8 consecutive i (one slot) of a row ----
    const int prow = tid >> 2;            // 0..63
    const int ps   = tid & 3;             // slot 0..3
    const int rsw  = (prow >> 1) & 3;     // row-pair slot swizzle
    __bf16* wp = &A_lds[0][0][prow][ps ^ rsw][0];
    const float* xp = x + (size_t)(bm + prow) * DIM + ps * 8;

    // ---- consumer A read base: row = mf*16 + l15, logical slot l4 ----
    const __bf16* abase = &A_lds[0][0][l15][l4 ^ ((l15 >> 1) & 3)][0];

    // ---- B lane base: granule (l4*DIM + cb + nf*16 + l15), 16B each ----
    const __bf16* wbase = W2 + ((size_t)l4 * DIM + cb + l15) * 8;

    // acc init from S0 (the k=0 term)
    const float* S0 = (const float*)W2;
    f32x4 acc[4][4];
#pragma unroll
    for (int nf = 0; nf < 4; ++nf) {
        float s0v = S0[cb + nf * 16 + l15];
#pragma unroll
        for (int mf = 0; mf < 4; ++mf)
#pragma unroll
            for (int r = 0; r < 4; ++r)
                acc[mf][nf][r] = s0v;
    }

    // ================= prologue =================
    // produce ic=S into buf 0 (serial, once)
    f32x4 xqa = *reinterpret_cast<const f32x4*>(xp + S * 32);
    f32x4 xqb = *reinterpret_cast<const f32x4*>(xp + S * 32 + 4);
    {
        float Tk[8], Tm[8], t2[8];
#pragma unroll
        for (int e = 0; e < 8; ++e) {
            float xv = (e < 4) ? xqa[e] : xqb[e - 4];
            float p = __builtin_amdgcn_exp2f(xv * 2.8853900817779268f);
            float t = 1.0f - 2.0f * __builtin_amdgcn_rcpf(p + 1.0f);
            Tk[e] = t;  t2[e] = t + t;  Tm[e] = 1.0f;
        }
#pragma unroll
        for (int kk = 0; kk < NK; ++kk) {
            bf16x8 v;
#pragma unroll
            for (int e = 0; e < 8; ++e) v[e] = (__bf16)Tk[e];
            *reinterpret_cast<bf16x8*>(wp + kk * 2048) = v;
            if (kk < NK - 1) {
#pragma unroll
                for (int e = 0; e < 8; ++e) {
                    float Tn = __builtin_fmaf(t2[e], Tk[e], -Tm[e]);
                    Tm[e] = Tk[e];  Tk[e] = Tn;
                }
            }
        }
    }
    // x((S+1)&15) for the first interleaved produce
    {
        const int ic1 = (S + 1) & (NIC - 1);
        xqa = *reinterpret_cast<const f32x4*>(xp + ic1 * 32);
        xqb = *reinterpret_cast<const f32x4*>(xp + ic1 * 32 + 4);
    }

    // B prologue: sets 0,1,2 = slabs (k=1..3, ic=S)
    bf16x8 bq[4][4];
#pragma unroll
    for (int s = 0; s < 3; ++s)
#pragma unroll
        for (int nf = 0; nf < 4; ++nf)
            bq[s][nf] = *reinterpret_cast<const bf16x8*>(
                wbase + (size_t)((s + 1) * 16 + S) * SLAB + nf * 128);

    asm volatile("s_waitcnt lgkmcnt(0)" ::: "memory");
    __builtin_amdgcn_s_barrier();

    // produce-state registers (live across ksteps within one body)
    float Tk[8], Tm[8], t2[8];

    // BODY: consume ic=ICC from buf BUF; produce (ICC+1)&15 into buf 1-BUF.
    // B-prefetch / x-load indices wrap mod 16 (always valid).
#define BODY(BUF, ICC, PROD)                                                     \
    {                                                                            \
        const int icn_  = ((ICC) + 1) & (NIC - 1);                               \
        const int icn2_ = ((ICC) + 2) & (NIC - 1);                               \
        _Pragma("unroll")                                                        \
        for (int k = 1; k <= NK; ++k) {                                          \
            /* B prefetch, 3 ksteps ahead, into set (k+2)&3 */                   \
            {                                                                    \
                const int nk  = (k <= 5) ? k + 3 : k - 5;                        \
                const int nic = (k <= 5) ? (ICC) : icn_;                         \
                const __bf16* np = wbase + (size_t)(nk * 16 + nic) * SLAB;       \
                _Pragma("unroll")                                                \
                for (int nf = 0; nf < 4; ++nf)                                   \
                    bq[(k + 2) & 3][nf] =                                        \
                        *reinterpret_cast<const bf16x8*>(np + nf * 128);         \
            }                                                                    \
            /* A frags from LDS (conflict-free swizzled) */                      \
            bf16x8 af[4];                                                        \
            _Pragma("unroll")                                                    \
            for (int mf = 0; mf < 4; ++mf)                                       \
                af[mf] = *reinterpret_cast<const bf16x8*>(                       \
                    abase + (BUF) * 16384 + (k - 1) * 2048 + mf * 512);          \
            /* 16 MFMA on set (k-1)&3 */                                         \
            __builtin_amdgcn_s_setprio(1);                                       \
            _Pragma("unroll")                                                    \
            for (int nf = 0; nf < 4; ++nf)                                       \
                _Pragma("unroll")                                                \
                for (int mf = 0; mf < 4; ++mf)                                   \
                    acc[mf][nf] = __builtin_amdgcn_mfma_f32_16x16x32_bf16(       \
                        af[mf], bq[(k - 1) & 3][nf], acc[mf][nf], 0, 0, 0);      \
            __builtin_amdgcn_s_setprio(0);                                       \
            /* interleaved produce of (ICC+1)&15 into the other buffer */        \
            if (PROD) {                                                          \
                if (k == 1) {                                                    \
                    _Pragma("unroll")                                            \
                    for (int e = 0; e < 8; ++e) {                                \
                        float xv = (e < 4) ? xqa[e] : xqb[e - 4];                \
                        float p = __builtin_amdgcn_exp2f(                        \
                            xv * 2.8853900817779268f);                           \
                        float t = 1.0f - 2.0f * __builtin_amdgcn_rcpf(p + 1.0f); \
                        Tk[e] = t;  t2[e] = t + t;  Tm[e] = 1.0f;                \
                    }                                                            \
                } else {                                                         \
                    _Pragma("unroll")                                            \
                    for (int e = 0; e < 8; ++e) {                                \
                        float Tn = __builtin_fmaf(t2[e], Tk[e], -Tm[e]);         \
                        Tm[e] = Tk[e];  Tk[e] = Tn;                              \
                    }                                                            \
                }                                                                \
                bf16x8 v;                                                        \
                _Pragma("unroll")                                                \
                for (int e = 0; e < 8; ++e) v[e] = (__bf16)Tk[e];                \
                *reinterpret_cast<bf16x8*>(                                      \
                    wp + (1 - (BUF)) * 16384 + (k - 1) * 2048) = v;              \
            }                                                                    \
            if (k == 2) {                                                        \
                xqa = *reinterpret_cast<const f32x4*>(xp + icn2_ * 32);          \
                xqb = *reinterpret_cast<const f32x4*>(xp + icn2_ * 32 + 4);      \
            }                                                                    \
        }                                                                        \
        if (PROD) {                                                              \
            asm volatile("s_waitcnt lgkmcnt(0)" ::: "memory");                   \
            __builtin_amdgcn_s_barrier();                                        \
        }                                                                        \
    }

    // 16 bodies, cyclic from S; last body has no produce.
    int icc = S;
    for (int j = 0; j < 7; ++j) {
        BODY(0, icc, 1);  icc = (icc + 1) & (NIC - 1);
        BODY(1, icc, 1);  icc = (icc + 1) & (NIC - 1);
    }
    BODY(0, icc, 1);  icc = (icc + 1) & (NIC - 1);
    BODY(1, icc, 0);
#undef BODY

    // ---- epilogue: C/D layout col=lane&15, row=(lane>>4)*4+r ----
#pragma unroll
    for (int mf = 0; mf < 4; ++mf)
#pragma unroll
        for (int r = 0; r < 4; ++r) {
            const int row = bm + mf * 16 + l4 * 4 + r;
            float* orow = out + (size_t)row * DIM + cb + l15;
#pragma unroll
            for (int nf = 0; nf < 4; ++nf)
                orow[nf * 16] = acc[mf][nf][r];
        }
}

extern "C" void kernel_launch(void* const* d_in, const int* in_sizes, int n_in,
                              void* d_out, int out_size, void* d_ws, size_t ws_size,
                              hipStream_t stream) {
    const float* x      = (const float*)d_in[0];   // (16384, 512)
    const float* coeffs = (const float*)d_in[1];   // (512, 512, 9)
    float* out          = (float*)d_out;           // (16384, 512)
    __bf16* W2          = (__bf16*)d_ws;           // 144*16384 bf16 = 4.7MB

    pack_w_kernel<<<(DIM * 64) / 256, 256, 0, stream>>>(coeffs, W2);
    s0_kernel<<<DIM, 64, 0, stream>>>(coeffs, (float*)W2);

    // grid = 2 n-halves x 256 m-blocks = 512 blocks of 256 thr = 2 blocks/CU
    // = 8 waves/CU = 2/SIMD (one wave of each co-resident block per SIMD).
    // nhalf = bid&1 == XCD parity -> each XCD L2 holds one 2.36MB W2 half.
    cheby_gemm_kernel<<<512, 256, 0, stream>>>(x, W2, out);
}

// Round 20
// 77.873 us; speedup vs baseline: 1.0210x; 1.0210x over previous
//
#include <hip/hip_runtime.h>
#include <hip/hip_bf16.h>

// ChebyKANLinear: y[b,j] = sum_i sum_k T_k(tanh(x[b,i])) * C[i,j,k]
// GEMM: M=16384, N=512, K=4608 (kflat = k*512 + i), k=0 folded into S0[j].
// v19 = v16 (balanced 64x64 wave tile; XCD-parity N-split -> W2 half
//   L2-resident; depth-3 B reg prefetch; 1 barrier/ic; zero-conflict LDS)
//   + DEFERRED PRODUCE-WRITE BURST: the interleaved per-kstep ds_write forced
//   an in-order lgkmcnt full-drain before every MFMA cluster (ds_write older
//   than the A ds_reads in the queue). Produce now accumulates into 8 bf16x8
//   REGISTERS; all 8 ds_write_b128 issue as one burst at body end, right
//   before the mandatory drain+barrier. Consume loop LDS ops = 4 A-reads
//   only -> compiler can pipeline them across ksteps (m97 behavior).

typedef __bf16 bf16x8 __attribute__((ext_vector_type(8)));
typedef float  f32x4  __attribute__((ext_vector_type(4)));

#define DIM  512
#define KDEG 9
#define NK   8               // k = 1..8 (k=0 folded into S0)
#define NIC  16
#define SLAB (4 * DIM * 8)   // 16384 bf16 per (k,ic) slab of W2

// ---- pack: C[i][j][k] -> W2[(k*16+ic)][s][j][e] (bf16), i = ic*32 + s*8 + e ----
__global__ void pack_w_kernel(const float* __restrict__ coeffs,
                              __bf16* __restrict__ W2) {
    int t  = blockIdx.x * blockDim.x + threadIdx.x;   // 32768 threads
    int j  = t & (DIM - 1);
    int s  = (t >> 9) & 3;
    int ic = t >> 11;

    bf16x8 v[KDEG];
#pragma unroll
    for (int e = 0; e < 8; ++e) {
        int i = ic * 32 + s * 8 + e;
        const float* src = coeffs + ((size_t)i * DIM + j) * KDEG;
#pragma unroll
        for (int k = 0; k < KDEG; ++k)
            v[k][e] = (__bf16)src[k];
    }
#pragma unroll
    for (int k = 0; k < KDEG; ++k) {
        size_t off = (size_t)(k * 16 + ic) * SLAB + ((size_t)s * DIM + j) * 8;
        *reinterpret_cast<bf16x8*>(W2 + off) = v[k];
    }
}

// ---- S0[j] = sum_i C[i][j][0] (f32) into W2's k=0 slab (GEMM never reads it) ----
__global__ void s0_kernel(const float* __restrict__ coeffs,
                          float* __restrict__ S0) {
    const int j    = blockIdx.x;      // 512 blocks
    const int lane = threadIdx.x;     // 64
    float s = 0.0f;
#pragma unroll
    for (int i = lane; i < DIM; i += 64)
        s += coeffs[((size_t)i * DIM + j) * KDEG];
#pragma unroll
    for (int off = 32; off > 0; off >>= 1)
        s += __shfl_down(s, off, 64);
    if (lane == 0) S0[j] = s;
}

// ---------------- fused GEMM: consume(ic) with produce(ic+1) in registers -------
__global__ __launch_bounds__(256, 2) void cheby_gemm_kernel(
    const float* __restrict__ x,
    const __bf16* __restrict__ W2,
    float* __restrict__ out)
{
    // double-buffered A-tile: [buf][kk][row(64)][slot(4)][8] bf16, 2 x 32KB
    __shared__ __bf16 A_lds[2][NK][64][4][8];

    const int tid   = threadIdx.x;
    const int lane  = tid & 63;
    const int wid   = tid >> 6;      // 0..3 = n-group (64 cols each)
    const int l15   = lane & 15;
    const int l4    = lane >> 4;     // 0..3
    const int nhalf = blockIdx.x & 1;            // == XCD parity (XCD = bid%8)
    const int bm    = (blockIdx.x >> 1) * 64;
    const int cb    = nhalf * 256 + wid * 64;    // wave's column base

    // ---- producer mapping: thread owns 8 consecutive i (one slot) of a row ----
    const int prow = tid >> 2;            // 0..63
    const int ps   = tid & 3;             // slot 0..3
    const int rsw  = (prow >> 1) & 3;     // row-pair slot swizzle
    __bf16* wp = &A_lds[0][0][prow][ps ^ rsw][0];
    const float* xp = x + (size_t)(bm + prow) * DIM + ps * 8;

    // ---- consumer A read base: row = mf*16 + l15, logical slot l4 ----
    const __bf16* abase = &A_lds[0][0][l15][l4 ^ ((l15 >> 1) & 3)][0];

    // ---- B lane base: granule (l4*DIM + cb + nf*16 + l15), 16B each ----
    const __bf16* wbase = W2 + ((size_t)l4 * DIM + cb + l15) * 8;

    // acc init from S0 (the k=0 term)
    const float* S0 = (const float*)W2;
    f32x4 acc[4][4];
#pragma unroll
    for (int nf = 0; nf < 4; ++nf) {
        float s0v = S0[cb + nf * 16 + l15];
#pragma unroll
        for (int mf = 0; mf < 4; ++mf)
#pragma unroll
            for (int r = 0; r < 4; ++r)
                acc[mf][nf][r] = s0v;
    }

    // ================= prologue =================
    // x(0); produce ic=0 into buf 0 (serial, once)
    f32x4 xqa = *reinterpret_cast<const f32x4*>(xp);
    f32x4 xqb = *reinterpret_cast<const f32x4*>(xp + 4);
    {
        float Tk[8], Tm[8], t2[8];
#pragma unroll
        for (int e = 0; e < 8; ++e) {
            float xv = (e < 4) ? xqa[e] : xqb[e - 4];
            float p = __builtin_amdgcn_exp2f(xv * 2.8853900817779268f);
            float t = 1.0f - 2.0f * __builtin_amdgcn_rcpf(p + 1.0f);
            Tk[e] = t;  t2[e] = t + t;  Tm[e] = 1.0f;
        }
#pragma unroll
        for (int kk = 0; kk < NK; ++kk) {
            bf16x8 v;
#pragma unroll
            for (int e = 0; e < 8; ++e) v[e] = (__bf16)Tk[e];
            *reinterpret_cast<bf16x8*>(wp + kk * 2048) = v;
            if (kk < NK - 1) {
#pragma unroll
                for (int e = 0; e < 8; ++e) {
                    float Tn = __builtin_fmaf(t2[e], Tk[e], -Tm[e]);
                    Tm[e] = Tk[e];  Tk[e] = Tn;
                }
            }
        }
    }
    // x(1) for the first interleaved produce
    xqa = *reinterpret_cast<const f32x4*>(xp + 32);
    xqb = *reinterpret_cast<const f32x4*>(xp + 36);

    // B prologue: sets 0,1,2 = slabs (k=1..3, ic=0)
    bf16x8 bq[4][4];
#pragma unroll
    for (int s = 0; s < 3; ++s)
#pragma unroll
        for (int nf = 0; nf < 4; ++nf)
            bq[s][nf] = *reinterpret_cast<const bf16x8*>(
                wbase + (size_t)((s + 1) * 16) * SLAB + nf * 128);

    asm volatile("s_waitcnt lgkmcnt(0)" ::: "memory");
    __builtin_amdgcn_s_barrier();

    // produce-state registers (live across ksteps within one body)
    float Tk[8], Tm[8], t2[8];

    // BODY: consume ic from buf BUF; produce ic+1 into REGISTERS pv[8], then
    // burst-write them to buf 1-BUF at body end (before the drain+barrier).
#define BODY(BUF, IC, PROD, XLOAD, PREFX)                                        \
    {                                                                            \
        bf16x8 pv[NK];                                                           \
        _Pragma("unroll")                                                        \
        for (int k = 1; k <= NK; ++k) {                                          \
            /* B prefetch, 3 ksteps ahead, into set (k+2)&3 */                   \
            if (k <= 5 || PREFX) {                                               \
                const int nk  = (k <= 5) ? k + 3 : k - 5;                        \
                const int nic = (k <= 5) ? (IC) : (IC) + 1;                      \
                const __bf16* np = wbase + (size_t)(nk * 16 + nic) * SLAB;       \
                _Pragma("unroll")                                                \
                for (int nf = 0; nf < 4; ++nf)                                   \
                    bq[(k + 2) & 3][nf] =                                        \
                        *reinterpret_cast<const bf16x8*>(np + nf * 128);         \
            }                                                                    \
            /* A frags from LDS (only LDS ops in the loop -> pipelineable) */    \
            bf16x8 af[4];                                                        \
            _Pragma("unroll")                                                    \
            for (int mf = 0; mf < 4; ++mf)                                       \
                af[mf] = *reinterpret_cast<const bf16x8*>(                       \
                    abase + (BUF) * 16384 + (k - 1) * 2048 + mf * 512);          \
            /* 16 MFMA on set (k-1)&3 */                                         \
            __builtin_amdgcn_s_setprio(1);                                       \
            _Pragma("unroll")                                                    \
            for (int nf = 0; nf < 4; ++nf)                                       \
                _Pragma("unroll")                                                \
                for (int mf = 0; mf < 4; ++mf)                                   \
                    acc[mf][nf] = __builtin_amdgcn_mfma_f32_16x16x32_bf16(       \
                        af[mf], bq[(k - 1) & 3][nf], acc[mf][nf], 0, 0, 0);      \
            __builtin_amdgcn_s_setprio(0);                                       \
            /* produce of ic+1: recurrence into REGISTERS (no LDS ops) */        \
            if (PROD) {                                                          \
                if (k == 1) {                                                    \
                    _Pragma("unroll")                                            \
                    for (int e = 0; e < 8; ++e) {                                \
                        float xv = (e < 4) ? xqa[e] : xqb[e - 4];                \
                        float p = __builtin_amdgcn_exp2f(                        \
                            xv * 2.8853900817779268f);                           \
                        float t = 1.0f - 2.0f * __builtin_amdgcn_rcpf(p + 1.0f); \
                        Tk[e] = t;  t2[e] = t + t;  Tm[e] = 1.0f;                \
                    }                                                            \
                } else {                                                         \
                    _Pragma("unroll")                                            \
                    for (int e = 0; e < 8; ++e) {                                \
                        float Tn = __builtin_fmaf(t2[e], Tk[e], -Tm[e]);         \
                        Tm[e] = Tk[e];  Tk[e] = Tn;                              \
                    }                                                            \
                }                                                                \
                _Pragma("unroll")                                                \
                for (int e = 0; e < 8; ++e) pv[k - 1][e] = (__bf16)Tk[e];        \
            }                                                                    \
            if (XLOAD && k == 2) {                                               \
                xqa = *reinterpret_cast<const f32x4*>(xp + ((IC) + 2) * 32);     \
                xqb = *reinterpret_cast<const f32x4*>(xp + ((IC) + 2) * 32 + 4); \
            }                                                                    \
        }                                                                        \
        if (PROD) {                                                              \
            /* burst write of the produced basis, then drain + barrier */        \
            _Pragma("unroll")                                                    \
            for (int kk = 0; kk < NK; ++kk)                                      \
                *reinterpret_cast<bf16x8*>(                                      \
                    wp + (1 - (BUF)) * 16384 + kk * 2048) = pv[kk];              \
            asm volatile("s_waitcnt lgkmcnt(0)" ::: "memory");                   \
            __builtin_amdgcn_s_barrier();                                        \
        }                                                                        \
    }

    // main: ic = 0..13 (full pipeline; x(ic+2) <= x(15) always valid)
    for (int icp = 0; icp < 14; icp += 2) {
        BODY(0, icp,     1, 1, 1);
        BODY(1, icp + 1, 1, 1, 1);
    }
    // tail: ic=14 (produce 15, no x-load), ic=15 (drain)
    BODY(0, 14, 1, 0, 1);
    BODY(1, 15, 0, 0, 0);
#undef BODY

    // ---- epilogue: C/D layout col=lane&15, row=(lane>>4)*4+r ----
#pragma unroll
    for (int mf = 0; mf < 4; ++mf)
#pragma unroll
        for (int r = 0; r < 4; ++r) {
            const int row = bm + mf * 16 + l4 * 4 + r;
            float* orow = out + (size_t)row * DIM + cb + l15;
#pragma unroll
            for (int nf = 0; nf < 4; ++nf)
                orow[nf * 16] = acc[mf][nf][r];
        }
}

extern "C" void kernel_launch(void* const* d_in, const int* in_sizes, int n_in,
                              void* d_out, int out_size, void* d_ws, size_t ws_size,
                              hipStream_t stream) {
    const float* x      = (const float*)d_in[0];   // (16384, 512)
    const float* coeffs = (const float*)d_in[1];   // (512, 512, 9)
    float* out          = (float*)d_out;           // (16384, 512)
    __bf16* W2          = (__bf16*)d_ws;           // 144*16384 bf16 = 4.7MB

    pack_w_kernel<<<(DIM * 64) / 256, 256, 0, stream>>>(coeffs, W2);
    s0_kernel<<<DIM, 64, 0, stream>>>(coeffs, (float*)W2);

    // grid = 2 n-halves x 256 m-blocks = 512 blocks of 256 thr = 2 blocks/CU
    // = 8 waves/CU. nhalf = bid&1 == XCD parity -> each XCD L2 holds one
    // 2.36MB W2 half, fully resident. Wave tile 64x64: A-LDS 23us, B-L1 23us,
    // both under the 37us matrix floor.
    cheby_gemm_kernel<<<512, 256, 0, stream>>>(x, W2, out);
}

// Round 22
// 77.109 us; speedup vs baseline: 1.0311x; 1.0099x over previous
//
#include <hip/hip_runtime.h>
#include <hip/hip_bf16.h>

// ChebyKANLinear: y[b,j] = sum_i sum_k T_k(tanh(x[b,i])) * C[i,j,k]
// GEMM: M=16384, N=512, K=4608 (kflat = k*512 + i), k=0 folded into S0[j].
// v21 = v16 (balanced 64x64 wave tile; XCD-parity N-split -> W2 half
//   L2-resident; interleaved produce/consume; depth-3 B reg prefetch;
//   1 barrier/ic; zero-conflict LDS swizzle) + S_SLEEP TEMPORAL STAGGER:
//   co-resident blocks (bid, bid+256) share a CU, run identical code from
//   the same instant -> their ~600cyc wave chains execute serially per SIMD
//   (measured: slot 1238cyc = 2x chain; MfmaUtil 45% = 90% of the fill
//   ceiling at this runtime). One block of each pair sleeps ~192cyc once
//   (half a chain) to flip the pair into anti-phase. s_sleep has ZERO
//   memory/register surface (v20's dummy-MFMA stagger tripped a post-timing
//   divergence via an unidentified codegen hazard; this probe removes that
//   surface entirely).

typedef __bf16 bf16x8 __attribute__((ext_vector_type(8)));
typedef float  f32x4  __attribute__((ext_vector_type(4)));

#define DIM  512
#define KDEG 9
#define NK   8               // k = 1..8 (k=0 folded into S0)
#define NIC  16
#define SLAB (4 * DIM * 8)   // 16384 bf16 per (k,ic) slab of W2

// ---- pack: C[i][j][k] -> W2[(k*16+ic)][s][j][e] (bf16), i = ic*32 + s*8 + e ----
__global__ void pack_w_kernel(const float* __restrict__ coeffs,
                              __bf16* __restrict__ W2) {
    int t  = blockIdx.x * blockDim.x + threadIdx.x;   // 32768 threads
    int j  = t & (DIM - 1);
    int s  = (t >> 9) & 3;
    int ic = t >> 11;

    bf16x8 v[KDEG];
#pragma unroll
    for (int e = 0; e < 8; ++e) {
        int i = ic * 32 + s * 8 + e;
        const float* src = coeffs + ((size_t)i * DIM + j) * KDEG;
#pragma unroll
        for (int k = 0; k < KDEG; ++k)
            v[k][e] = (__bf16)src[k];
    }
#pragma unroll
    for (int k = 0; k < KDEG; ++k) {
        size_t off = (size_t)(k * 16 + ic) * SLAB + ((size_t)s * DIM + j) * 8;
        *reinterpret_cast<bf16x8*>(W2 + off) = v[k];
    }
}

// ---- S0[j] = sum_i C[i][j][0] (f32) into W2's k=0 slab (GEMM never reads it) ----
__global__ void s0_kernel(const float* __restrict__ coeffs,
                          float* __restrict__ S0) {
    const int j    = blockIdx.x;      // 512 blocks
    const int lane = threadIdx.x;     // 64
    float s = 0.0f;
#pragma unroll
    for (int i = lane; i < DIM; i += 64)
        s += coeffs[((size_t)i * DIM + j) * KDEG];
#pragma unroll
    for (int off = 32; off > 0; off >>= 1)
        s += __shfl_down(s, off, 64);
    if (lane == 0) S0[j] = s;
}

// ---------------- fused GEMM: consume(ic) with produce(ic+1) interleaved --------
__global__ __launch_bounds__(256, 2) void cheby_gemm_kernel(
    const float* __restrict__ x,
    const __bf16* __restrict__ W2,
    float* __restrict__ out)
{
    // double-buffered A-tile: [buf][kk][row(64)][slot(4)][8] bf16, 2 x 32KB
    __shared__ __bf16 A_lds[2][NK][64][4][8];

    const int tid   = threadIdx.x;
    const int lane  = tid & 63;
    const int wid   = tid >> 6;      // 0..3 = n-group (64 cols each)
    const int l15   = lane & 15;
    const int l4    = lane >> 4;     // 0..3
    const int nhalf = blockIdx.x & 1;            // == XCD parity (XCD = bid%8)
    const int bm    = (blockIdx.x >> 1) * 64;
    const int cb    = nhalf * 256 + wid * 64;    // wave's column base

    // ---- producer mapping: thread owns 8 consecutive i (one slot) of a row ----
    const int prow = tid >> 2;            // 0..63
    const int ps   = tid & 3;             // slot 0..3
    const int rsw  = (prow >> 1) & 3;     // row-pair slot swizzle
    __bf16* wp = &A_lds[0][0][prow][ps ^ rsw][0];
    const float* xp = x + (size_t)(bm + prow) * DIM + ps * 8;

    // ---- consumer A read base: row = mf*16 + l15, logical slot l4 ----
    const __bf16* abase = &A_lds[0][0][l15][l4 ^ ((l15 >> 1) & 3)][0];

    // ---- B lane base: granule (l4*DIM + cb + nf*16 + l15), 16B each ----
    const __bf16* wbase = W2 + ((size_t)l4 * DIM + cb + l15) * 8;

    // acc init from S0 (the k=0 term)
    const float* S0 = (const float*)W2;
    f32x4 acc[4][4];
#pragma unroll
    for (int nf = 0; nf < 4; ++nf) {
        float s0v = S0[cb + nf * 16 + l15];
#pragma unroll
        for (int mf = 0; mf < 4; ++mf)
#pragma unroll
            for (int r = 0; r < 4; ++r)
                acc[mf][nf][r] = s0v;
    }

    // ================= prologue =================
    // x(0); produce ic=0 into buf 0 (serial, once)
    f32x4 xqa = *reinterpret_cast<const f32x4*>(xp);
    f32x4 xqb = *reinterpret_cast<const f32x4*>(xp + 4);
    {
        float Tk[8], Tm[8], t2[8];
#pragma unroll
        for (int e = 0; e < 8; ++e) {
            float xv = (e < 4) ? xqa[e] : xqb[e - 4];
            float p = __builtin_amdgcn_exp2f(xv * 2.8853900817779268f);
            float t = 1.0f - 2.0f * __builtin_amdgcn_rcpf(p + 1.0f);
            Tk[e] = t;  t2[e] = t + t;  Tm[e] = 1.0f;
        }
#pragma unroll
        for (int kk = 0; kk < NK; ++kk) {
            bf16x8 v;
#pragma unroll
            for (int e = 0; e < 8; ++e) v[e] = (__bf16)Tk[e];
            *reinterpret_cast<bf16x8*>(wp + kk * 2048) = v;
            if (kk < NK - 1) {
#pragma unroll
                for (int e = 0; e < 8; ++e) {
                    float Tn = __builtin_fmaf(t2[e], Tk[e], -Tm[e]);
                    Tm[e] = Tk[e];  Tk[e] = Tn;
                }
            }
        }
    }
    // x(1) for the first interleaved produce
    xqa = *reinterpret_cast<const f32x4*>(xp + 32);
    xqb = *reinterpret_cast<const f32x4*>(xp + 36);

    // B prologue: sets 0,1,2 = slabs (k=1..3, ic=0)
    bf16x8 bq[4][4];
#pragma unroll
    for (int s = 0; s < 3; ++s)
#pragma unroll
        for (int nf = 0; nf < 4; ++nf)
            bq[s][nf] = *reinterpret_cast<const bf16x8*>(
                wbase + (size_t)((s + 1) * 16) * SLAB + nf * 128);

    asm volatile("s_waitcnt lgkmcnt(0)" ::: "memory");
    __builtin_amdgcn_s_barrier();

    // ---- temporal stagger: pure time-shift, zero memory/register surface.
    //      One block of each co-resident pair (bid, bid+256) sleeps ~192cyc
    //      (≈ half a wave chain) to flip the pair into anti-phase.
    if ((blockIdx.x >> 8) & 1)
        __builtin_amdgcn_s_sleep(3);

    // produce-state registers (live across ksteps within one body)
    float Tk[8], Tm[8], t2[8];

    // BODY: consume ic from buf BUF; optionally produce ic+1 into buf 1-BUF.
#define BODY(BUF, IC, PROD, XLOAD, PREFX)                                        \
    {                                                                            \
        _Pragma("unroll")                                                        \
        for (int k = 1; k <= NK; ++k) {                                          \
            /* B prefetch, 3 ksteps ahead, into set (k+2)&3 */                   \
            if (k <= 5 || PREFX) {                                               \
                const int nk  = (k <= 5) ? k + 3 : k - 5;                        \
                const int nic = (k <= 5) ? (IC) : (IC) + 1;                      \
                const __bf16* np = wbase + (size_t)(nk * 16 + nic) * SLAB;       \
                _Pragma("unroll")                                                \
                for (int nf = 0; nf < 4; ++nf)                                   \
                    bq[(k + 2) & 3][nf] =                                        \
                        *reinterpret_cast<const bf16x8*>(np + nf * 128);         \
            }                                                                    \
            /* A frags from LDS (conflict-free swizzled) */                      \
            bf16x8 af[4];                                                        \
            _Pragma("unroll")                                                    \
            for (int mf = 0; mf < 4; ++mf)                                       \
                af[mf] = *reinterpret_cast<const bf16x8*>(                       \
                    abase + (BUF) * 16384 + (k - 1) * 2048 + mf * 512);          \
            /* 16 MFMA on set (k-1)&3 */                                         \
            __builtin_amdgcn_s_setprio(1);                                       \
            _Pragma("unroll")                                                    \
            for (int nf = 0; nf < 4; ++nf)                                       \
                _Pragma("unroll")                                                \
                for (int mf = 0; mf < 4; ++mf)                                   \
                    acc[mf][nf] = __builtin_amdgcn_mfma_f32_16x16x32_bf16(       \
                        af[mf], bq[(k - 1) & 3][nf], acc[mf][nf], 0, 0, 0);      \
            __builtin_amdgcn_s_setprio(0);                                       \
            /* interleaved produce of ic+1 into the other buffer */              \
            if (PROD) {                                                          \
                if (k == 1) {                                                    \
                    _Pragma("unroll")                                            \
                    for (int e = 0; e < 8; ++e) {                                \
                        float xv = (e < 4) ? xqa[e] : xqb[e - 4];                \
                        float p = __builtin_amdgcn_exp2f(                        \
                            xv * 2.8853900817779268f);                           \
                        float t = 1.0f - 2.0f * __builtin_amdgcn_rcpf(p + 1.0f); \
                        Tk[e] = t;  t2[e] = t + t;  Tm[e] = 1.0f;                \
                    }                                                            \
                } else {                                                         \
                    _Pragma("unroll")                                            \
                    for (int e = 0; e < 8; ++e) {                                \
                        float Tn = __builtin_fmaf(t2[e], Tk[e], -Tm[e]);         \
                        Tm[e] = Tk[e];  Tk[e] = Tn;                              \
                    }                                                            \
                }                                                                \
                bf16x8 v;                                                        \
                _Pragma("unroll")                                                \
                for (int e = 0; e < 8; ++e) v[e] = (__bf16)Tk[e];                \
                *reinterpret_cast<bf16x8*>(                                      \
                    wp + (1 - (BUF)) * 16384 + (k - 1) * 2048) = v;              \
            }                                                                    \
            if (XLOAD && k == 2) {                                               \
                xqa = *reinterpret_cast<const f32x4*>(xp + ((IC) + 2) * 32);     \
                xqb = *reinterpret_cast<const f32x4*>(xp + ((IC) + 2) * 32 + 4); \
            }                                                                    \
        }                                                                        \
        if (PROD) {                                                              \
            asm volatile("s_waitcnt lgkmcnt(0)" ::: "memory");                   \
            __builtin_amdgcn_s_barrier();                                        \
        }                                                                        \
    }

    // main: ic = 0..13 (full pipeline; x(ic+2) <= x(15) always valid)
    for (int icp = 0; icp < 14; icp += 2) {
        BODY(0, icp,     1, 1, 1);
        BODY(1, icp + 1, 1, 1, 1);
    }
    // tail: ic=14 (produce 15, no x-load), ic=15 (drain)
    BODY(0, 14, 1, 0, 1);
    BODY(1, 15, 0, 0, 0);
#undef BODY

    // ---- epilogue: C/D layout col=lane&15, row=(lane>>4)*4+r ----
#pragma unroll
    for (int mf = 0; mf < 4; ++mf)
#pragma unroll
        for (int r = 0; r < 4; ++r) {
            const int row = bm + mf * 16 + l4 * 4 + r;
            float* orow = out + (size_t)row * DIM + cb + l15;
#pragma unroll
            for (int nf = 0; nf < 4; ++nf)
                orow[nf * 16] = acc[mf][nf][r];
        }
}

extern "C" void kernel_launch(void* const* d_in, const int* in_sizes, int n_in,
                              void* d_out, int out_size, void* d_ws, size_t ws_size,
                              hipStream_t stream) {
    const float* x      = (const float*)d_in[0];   // (16384, 512)
    const float* coeffs = (const float*)d_in[1];   // (512, 512, 9)
    float* out          = (float*)d_out;           // (16384, 512)
    __bf16* W2          = (__bf16*)d_ws;           // 144*16384 bf16 = 4.7MB

    pack_w_kernel<<<(DIM * 64) / 256, 256, 0, stream>>>(coeffs, W2);
    s0_kernel<<<DIM, 64, 0, stream>>>(coeffs, (float*)W2);

    // grid = 2 n-halves x 256 m-blocks = 512 blocks of 256 thr = 2 blocks/CU
    // = 8 waves/CU. nhalf = bid&1 == XCD parity -> each XCD L2 holds one
    // 2.36MB W2 half, fully resident. Wave tile 64x64: A-LDS 23us, B-L1 23us,
    // both under the 37us matrix floor.
    cheby_gemm_kernel<<<512, 256, 0, stream>>>(x, W2, out);
}